// Round 2
// baseline (259.952 us; speedup 1.0000x reference)
//
#include <hip/hip_runtime.h>
#include <hip/hip_bf16.h>
#include <math.h>

// Problem constants: ip (8, 256, 128, 128) fp32 -> DCT-III along channels.
#define NB   8
#define NC   256
#define NHW  (128 * 128)

// GEMM tiling: Out[c,p] = sum_k M[c,k] X[k,p], per batch.
// Block = full c (256) x BN p, BK=32 k-step. 512 threads = 8 waves (4m x 2n),
// per-wave 64(c) x 32(p) -> acc[4][2] = 32 AGPRs.
#define BN   64
#define BK   32
#define LSTR 80   // LDS row stride bytes (64 B data + 16 pad; stride 5 bank-quads)

typedef __attribute__((ext_vector_type(4))) float f32x4;
typedef __attribute__((ext_vector_type(8))) short bf16x8;

__device__ __forceinline__ unsigned f2bf_hi(float f) {   // bf16 bits in high half
    unsigned u = __builtin_bit_cast(unsigned, f);
    u += 0x7fffu + ((u >> 16) & 1u);
    return u & 0xffff0000u;
}
__device__ __forceinline__ unsigned f2bf_lo(float f) {   // bf16 bits in low half
    unsigned u = __builtin_bit_cast(unsigned, f);
    u += 0x7fffu + ((u >> 16) & 1u);
    return u >> 16;
}

// DCT-III coefficient matrix, bf16 row-major [c][k]:
// M[c][k] = (k==0) ? 1 : 2*cos(pi*k*(2c+1)/512). Exact integer angle reduction.
__global__ void coef_kernel(unsigned short* __restrict__ coef) {
    int idx = blockIdx.x * 256 + threadIdx.x;
    int c = idx >> 8;
    int k = idx & 255;
    int t = (k * (2 * c + 1)) & 1023;
    float v = (k == 0) ? 1.0f : 2.0f * cosf((float)t * (float)(M_PI / 512.0));
    coef[idx] = (unsigned short)f2bf_lo(v);
}

// grid: (NHW/BN, NB). A-fragments read directly from global (M is L2-hot,
// 128 KB). X staged through double-buffered LDS (transpose+bf16 convert),
// software-pipelined one k-iter ahead.
__global__ __launch_bounds__(512, 4)
void dct_gemm(const float* __restrict__ X, const unsigned short* __restrict__ Mcoef,
              float* __restrict__ Out) {
    __shared__ unsigned char Xlds[2 * BN * LSTR];   // 10 KB

    const int tid  = threadIdx.x;
    const int lane = tid & 63;
    const int wave = tid >> 6;        // 0..7
    const int wm   = wave >> 1;       // 0..3 -> c quarter (64 rows)
    const int wn   = wave & 1;        // 0..1 -> p half (32 cols)
    const int m16  = lane & 15;
    const int quad = lane >> 4;

    const int p0 = blockIdx.x * BN;
    const float* Xb = X + (size_t)blockIdx.y * (NC * NHW);
    float* Ob = Out + (size_t)blockIdx.y * (NC * NHW);

    // staging role: p = p0 + sr, k-chunk of 4 at sh
    const int sr = tid & 63;
    const int sh = tid >> 6;          // 0..7

    f32x4 acc[4][2];
#pragma unroll
    for (int i = 0; i < 4; i++)
#pragma unroll
        for (int j = 0; j < 2; j++) acc[i][j] = (f32x4){0.f, 0.f, 0.f, 0.f};

    // A-fragment base: lane holds A[row][quad*8 .. +7], row = wm*64+mt*16+m16
    const unsigned short* Abase = Mcoef + (wm * 64 + m16) * NC + quad * 8;
    const float* Xsrc0 = Xb + p0 + sr;

    // ---- prefetch iter 0 ----
    float xv[4];
#pragma unroll
    for (int j = 0; j < 4; j++) xv[j] = Xsrc0[(sh * 4 + j) * NHW];
    bf16x8 afr[4];
#pragma unroll
    for (int mt = 0; mt < 4; mt++)
        afr[mt] = *(const bf16x8*)(Abase + mt * 16 * NC);

    for (int it = 0; it < NC / BK; ++it) {
        const int buf = (it & 1) * (BN * LSTR);

        // write current X regs -> LDS (bf16 pack, b64 per thread)
        {
            unsigned pk0 = f2bf_lo(xv[0]) | f2bf_hi(xv[1]);
            unsigned pk1 = f2bf_lo(xv[2]) | f2bf_hi(xv[3]);
            *(int2*)(Xlds + buf + sr * LSTR + sh * 8) = (int2){(int)pk0, (int)pk1};
        }
        __syncthreads();

        // prefetch next iter (wraps to 0 on last iter; harmless, keeps regs defined)
        const int nk0 = ((it + 1) & (NC / BK - 1)) * BK;
        float xn[4];
#pragma unroll
        for (int j = 0; j < 4; j++) xn[j] = Xsrc0[(nk0 + sh * 4 + j) * NHW];
        bf16x8 an[4];
#pragma unroll
        for (int mt = 0; mt < 4; mt++)
            an[mt] = *(const bf16x8*)(Abase + mt * 16 * NC + nk0);

        // B fragments from LDS
        bf16x8 bfr[2];
#pragma unroll
        for (int nt = 0; nt < 2; nt++) {
            int row = wn * 32 + nt * 16 + m16;
            bfr[nt] = *(const bf16x8*)(Xlds + buf + row * LSTR + quad * 16);
        }

#pragma unroll
        for (int mt = 0; mt < 4; mt++)
#pragma unroll
            for (int nt = 0; nt < 2; nt++)
                acc[mt][nt] = __builtin_amdgcn_mfma_f32_16x16x32_bf16(
                    afr[mt], bfr[nt], acc[mt][nt], 0, 0, 0);

#pragma unroll
        for (int j = 0; j < 4; j++) xv[j] = xn[j];
#pragma unroll
        for (int mt = 0; mt < 4; mt++) afr[mt] = an[mt];
    }

    // epilogue: D layout col = lane&15 (p), row = quad*4 + r (c)
#pragma unroll
    for (int mt = 0; mt < 4; mt++) {
#pragma unroll
        for (int nt = 0; nt < 2; nt++) {
            int cc = wm * 64 + mt * 16 + quad * 4;
            int pp = p0 + wn * 32 + nt * 16 + m16;
            float* o = Ob + cc * NHW + pp;
#pragma unroll
            for (int r = 0; r < 4; r++)
                o[r * NHW] = acc[mt][nt][r];
        }
    }
}

extern "C" void kernel_launch(void* const* d_in, const int* in_sizes, int n_in,
                              void* d_out, int out_size, void* d_ws, size_t ws_size,
                              hipStream_t stream) {
    const float* ip = (const float*)d_in[0];
    float* out = (float*)d_out;
    unsigned short* coef = (unsigned short*)d_ws;   // 128 KB scratch

    coef_kernel<<<dim3(256), dim3(256), 0, stream>>>(coef);

    dim3 grid(NHW / BN, NB);   // (256, 8) = 2048 blocks x 512 threads
    dct_gemm<<<grid, dim3(512), 0, stream>>>(ip, coef, out);
}